// Round 15
// baseline (118.389 us; speedup 1.0000x reference)
//
#include <hip/hip_runtime.h>
#include <hip/hip_fp16.h>

#define BLK 256
#define PBLK 1024             // threads per partition/refine block
#define NPB 256               // bucket-scatter blocks
#define CSHIFT 10             // 1024 dst nodes per coarse bucket
#define CNODES 1024
#define CMASK 1023
#define NBCMAX 128            // max coarse buckets (n <= 131072)
#define NREG 8                // XCD regions per bucket
#define CAPR 5376             // slots per (bucket,region); mean ~4082 + pad<=480, mult of 16
#define STCAP 96              // LDS stage rows per bucket (tile mean ~42 + carry 15)
#define SSHIFT 7              // slice bits 7..9 -> 8 slices of 128 nodes
#define SROWS 128
#define SRMASK 127
#define FCAP2 768             // slots per (bucket,slice,region); mean ~510
#define OVFCAP 8192
#define FXS 1048576.0f        // 2^20 fixed-point scale for LDS int accumulation
#define FXI (1.0f / 1048576.0f)

typedef int v4i __attribute__((ext_vector_type(4)));

static inline int cdiv(int a, int b) { return (a + b - 1) / b; }

// ---------------- staged coarse scatter: all slab writes are full 64B lines ----------------
__global__ void __launch_bounds__(PBLK)
k_bucket(const int* __restrict__ src, const int* __restrict__ dst,
         int* __restrict__ gcur, int* __restrict__ slab,
         int* __restrict__ ovf_cnt, int* __restrict__ ovf_b, int* __restrict__ ovf_e,
         int e, int nb) {
    __shared__ int scnt[NBCMAX];
    __shared__ int stage[NBCMAX][STCAP];
    int tid = threadIdx.x;
    int reg = blockIdx.x & (NREG - 1);
    for (int t = tid; t < nb; t += PBLK) scnt[t] = 0;
    __syncthreads();
    int per = ((e + (int)gridDim.x - 1) / (int)gridDim.x + 3) & ~3;
    int beg = blockIdx.x * per;
    int end = min(e, beg + per);
    for (int tbeg = beg; tbeg < end; tbeg += PBLK * 4) {
        // append phase
        int i = tbeg + tid * 4;
        if (i < end) {
            if (i + 3 < end) {
                v4i s4 = __builtin_nontemporal_load((const v4i*)(src + i));
                v4i d4 = __builtin_nontemporal_load((const v4i*)(dst + i));
#pragma unroll
                for (int k = 0; k < 4; ++k) {
                    int d = d4[k];
                    int b = d >> CSHIFT;
                    int entry = (s4[k] << CSHIFT) | (d & CMASK);
                    int pos = atomicAdd(&scnt[b], 1);
                    if (pos < STCAP) stage[b][pos] = entry;
                    else {
                        int oi = atomicAdd(ovf_cnt, 1);
                        if (oi < OVFCAP) { ovf_b[oi] = b; ovf_e[oi] = entry; }
                    }
                }
            } else {
                for (int k = 0; k < 4 && i + k < end; ++k) {
                    int d = dst[i + k];
                    int b = d >> CSHIFT;
                    int entry = (src[i + k] << CSHIFT) | (d & CMASK);
                    int pos = atomicAdd(&scnt[b], 1);
                    if (pos < STCAP) stage[b][pos] = entry;
                    else {
                        int oi = atomicAdd(ovf_cnt, 1);
                        if (oi < OVFCAP) { ovf_b[oi] = b; ovf_e[oi] = entry; }
                    }
                }
            }
        }
        __syncthreads();
        // flush phase: full 16-slot lines per bucket, one thread per bucket
        for (int bb = tid; bb < nb; bb += PBLK) {
            int cnt = min(scnt[bb], STCAP);
            int nl16 = cnt & ~15;
            if (nl16) {
                int creg = bb * NREG + reg;
                int base = atomicAdd(&gcur[creg], nl16);
                int fit = nl16;
                if (base >= CAPR) fit = 0;
                else if (base + nl16 > CAPR) fit = (CAPR - base) & ~15;
                int* dstp = slab + (size_t)creg * CAPR + base;
                for (int l = 0; l < fit; l += 16) {
                    int4* dp = reinterpret_cast<int4*>(dstp + l);
#pragma unroll
                    for (int q = 0; q < 4; ++q)
                        dp[q] = make_int4(stage[bb][l + 4 * q + 0], stage[bb][l + 4 * q + 1],
                                          stage[bb][l + 4 * q + 2], stage[bb][l + 4 * q + 3]);
                }
                // rare: lines that didn't fit -> overflow list; fill sub-CAPR gap with -1
                for (int x = fit; x < nl16; ++x) {
                    if (base + x < CAPR) dstp[x] = -1;
                    int oi = atomicAdd(ovf_cnt, 1);
                    if (oi < OVFCAP) { ovf_b[oi] = bb; ovf_e[oi] = stage[bb][x]; }
                }
                int rem = cnt - nl16;
                for (int k = 0; k < rem; ++k) stage[bb][k] = stage[bb][nl16 + k];
                scnt[bb] = rem;
            }
        }
        __syncthreads();
    }
    // final flush: pad remainder to a full line with -1
    for (int bb = tid; bb < nb; bb += PBLK) {
        int cnt = min(scnt[bb], STCAP);    // < 16 here
        if (cnt > 0) {
            int creg = bb * NREG + reg;
            int base = atomicAdd(&gcur[creg], 16);
            int* dstp = slab + (size_t)creg * CAPR + base;
            if (base + 16 <= CAPR) {
                int r[16];
#pragma unroll
                for (int k = 0; k < 16; ++k) r[k] = (k < cnt) ? stage[bb][k] : -1;
                int4* dp = reinterpret_cast<int4*>(dstp);
                dp[0] = make_int4(r[0], r[1], r[2], r[3]);
                dp[1] = make_int4(r[4], r[5], r[6], r[7]);
                dp[2] = make_int4(r[8], r[9], r[10], r[11]);
                dp[3] = make_int4(r[12], r[13], r[14], r[15]);
            } else {
                for (int x = base; x < CAPR; ++x) dstp[x - base] = -1;
                for (int k = 0; k < cnt; ++k) {
                    int oi = atomicAdd(ovf_cnt, 1);
                    if (oi < OVFCAP) { ovf_b[oi] = bb; ovf_e[oi] = stage[bb][k]; }
                }
            }
        }
    }
}

// ---------------- refine: block (b,reg) -> 8 fine segments + degree ----------------
__global__ void __launch_bounds__(PBLK)
k_refine(const int* __restrict__ gcur, const int* __restrict__ cslab,
         int* __restrict__ fslab, int* __restrict__ ftot,
         int* __restrict__ deg,
         const int* __restrict__ ovf_cnt, const int* __restrict__ ovf_b,
         const int* __restrict__ ovf_e, int n) {
    __shared__ int cur[8];
    __shared__ int cnt[CNODES];
    int tid = threadIdx.x;
    int b = blockIdx.x >> 3;
    int p = blockIdx.x & 7;
    if (tid < 8) cur[tid] = 0;
    for (int t = tid; t < CNODES; t += PBLK) cnt[t] = 0;
    __syncthreads();
    int creg = b * NREG + p;
    int m = min(gcur[creg], CAPR);
    const v4i* sl4 = reinterpret_cast<const v4i*>(cslab + (size_t)creg * CAPR);
    for (int i = tid; i < (m >> 2); i += PBLK) {
        v4i e4 = sl4[i];
#pragma unroll
        for (int k = 0; k < 4; ++k) {
            int e = e4[k];
            if (e >= 0) {
                int s = (e >> SSHIFT) & 7;
                int fe = ((e >> CSHIFT) << SSHIFT) | (e & SRMASK);
                atomicAdd(&cnt[e & CMASK], 1);
                int pos = atomicAdd(&cur[s], 1);
                if (pos < FCAP2) fslab[(size_t)((b * 8 + s) * NREG + p) * FCAP2 + pos] = fe;
            }
        }
    }
    if (p == 0) {   // region-0 block also absorbs the (normally empty) overflow list
        int novf = min(*ovf_cnt, OVFCAP);
        for (int i = tid; i < novf; i += PBLK) {
            if (ovf_b[i] == b) {
                int e = ovf_e[i];
                int s = (e >> SSHIFT) & 7;
                int fe = ((e >> CSHIFT) << SSHIFT) | (e & SRMASK);
                atomicAdd(&cnt[e & CMASK], 1);
                int pos = atomicAdd(&cur[s], 1);
                if (pos < FCAP2) fslab[(size_t)((b * 8 + s) * NREG + 0) * FCAP2 + pos] = fe;
            }
        }
    }
    __syncthreads();
    if (tid < 8) {
        int cc = min(cur[tid], FCAP2);
        int r = min((cc + 15) & ~15, FCAP2);
        int* seg = fslab + (size_t)((b * 8 + tid) * NREG + p) * FCAP2;
        for (int x = cc; x < r; ++x) seg[x] = -1;
        ftot[(b * 8 + tid) * NREG + p] = r;
    }
    for (int t = tid; t < CNODES; t += PBLK) {
        int v = cnt[t];
        int nd = b * CNODES + t;
        if (v && nd < n) atomicAdd(&deg[nd], v);
    }
}

// ---------------- fused: feature encode -> @W0 -> *dinv -> Hs[n,16] (f16) ----------------
__global__ void k_featmm(const int* __restrict__ feat,
                         const float* __restrict__ emb_user,
                         const float* __restrict__ emb_known,
                         const float* __restrict__ w_user,
                         const float* __restrict__ b_user,
                         const float* __restrict__ emb_cat,
                         const float* __restrict__ w_cat,
                         const float* __restrict__ b_cat,
                         const float* __restrict__ w0,
                         const int* __restrict__ deg,
                         __half* __restrict__ Hs,
                         int n, int user_max, int cat_max) {
    __shared__ float w0s[8 * 16];
    for (int t = threadIdx.x; t < 8 * 16; t += blockDim.x) w0s[t] = w0[t];
    __syncthreads();
    int i = blockIdx.x * blockDim.x + threadIdx.x;
    if (i >= n) return;
    int col0 = feat[i * 3 + 0];
    int col1 = feat[i * 3 + 1];
    int typ  = feat[i * 3 + 2];
    float x[8];
    if (typ == 0) {
        int u = min(max(col0, 0), user_max);
        int k = min(max(col1, 0), 1);
        const float4* eu = reinterpret_cast<const float4*>(emb_user + (size_t)u * 8);
        const float4* ek = reinterpret_cast<const float4*>(emb_known + (size_t)k * 8);
        float4 a0 = eu[0], a1 = eu[1], k0 = ek[0], k1 = ek[1];
        float in[8];
        in[0] = fmaxf(a0.x + k0.x, 0.f); in[1] = fmaxf(a0.y + k0.y, 0.f);
        in[2] = fmaxf(a0.z + k0.z, 0.f); in[3] = fmaxf(a0.w + k0.w, 0.f);
        in[4] = fmaxf(a1.x + k1.x, 0.f); in[5] = fmaxf(a1.y + k1.y, 0.f);
        in[6] = fmaxf(a1.z + k1.z, 0.f); in[7] = fmaxf(a1.w + k1.w, 0.f);
#pragma unroll
        for (int c = 0; c < 8; ++c) {
            float s = b_user[c];
#pragma unroll
            for (int d = 0; d < 8; ++d) s += in[d] * w_user[d * 8 + c];
            x[c] = s;
        }
    } else {
        int ci = min(max(col0, 0), cat_max);
        float4 c0 = reinterpret_cast<const float4*>(emb_cat + (size_t)ci * 4)[0];
        float in[4];
        in[0] = fmaxf(c0.x, 0.f); in[1] = fmaxf(c0.y, 0.f);
        in[2] = fmaxf(c0.z, 0.f); in[3] = fmaxf(c0.w, 0.f);
#pragma unroll
        for (int c = 0; c < 8; ++c) {
            float s = b_cat[c];
#pragma unroll
            for (int d = 0; d < 4; ++d) s += in[d] * w_cat[d * 8 + c];
            x[c] = s;
        }
    }
    float dv = rsqrtf((float)deg[i] + 1.0f);
    float o[16];
#pragma unroll
    for (int c = 0; c < 16; ++c) {
        float s = 0.f;
#pragma unroll
        for (int d = 0; d < 8; ++d) s += x[d] * w0s[d * 16 + c];
        o[c] = s * dv;
    }
    union { __half2 h[8]; uint4 u[2]; } pk;
#pragma unroll
    for (int k = 0; k < 8; ++k) pk.h[k] = __floats2half2_rn(o[2 * k], o[2 * k + 1]);
    uint4* dp = reinterpret_cast<uint4*>(Hs + (size_t)i * 16);
    dp[0] = pk.u[0];
    dp[1] = pk.u[1];
}

// ---------------- paired-segment 8-deep gather ----------------
__device__ __forceinline__ void gather_pair(const int* __restrict__ run0, int n0,
                                            const int* __restrict__ run1, int n1,
                                            const uint4* __restrict__ Hs4,
                                            int (*acc)[17], int tid) {
    const v4i* sl0 = reinterpret_cast<const v4i*>(run0);
    const v4i* sl1 = reinterpret_cast<const v4i*>(run1);
    int ns0 = n0 >> 2, ns1 = n1 >> 2;
    int maxs = max(ns0, ns1);
    int g = tid >> 1, q = tid & 1;    // 128 lane-pairs; q owns 8 of 16 channels
    for (int base = 0; base < maxs; base += 128) {
        int i = base + g;
        v4i e0 = sl0[min(i, (FCAP2 >> 2) - 1)];
        v4i e1 = sl1[min(i, (FCAP2 >> 2) - 1)];
        bool b0 = i < ns0, b1 = i < ns1;
        int us[8];
        us[0] = b0 ? e0[0] : -1; us[1] = b0 ? e0[1] : -1;
        us[2] = b0 ? e0[2] : -1; us[3] = b0 ? e0[3] : -1;
        us[4] = b1 ? e1[0] : -1; us[5] = b1 ? e1[1] : -1;
        us[6] = b1 ? e1[2] : -1; us[7] = b1 ? e1[3] : -1;
        uint4 v[8];
#pragma unroll
        for (int k = 0; k < 8; ++k)
            if (us[k] >= 0) v[k] = Hs4[(size_t)(us[k] >> SSHIFT) * 2 + q];
#pragma unroll
        for (int k = 0; k < 8; ++k) {
            if (us[k] >= 0) {
                int dl = us[k] & SRMASK;
                union { uint4 u4; __half2 h[4]; } c;
                c.u4 = v[k];
#pragma unroll
                for (int j = 0; j < 4; ++j) {
                    float2 f = __half22float2(c.h[j]);
                    atomicAdd(&acc[dl][8 * q + 2 * j + 0], __float2int_rn(f.x * FXS));
                    atomicAdd(&acc[dl][8 * q + 2 * j + 1], __float2int_rn(f.y * FXS));
                }
            }
        }
    }
}

__device__ __forceinline__ void gather_fb(const int* __restrict__ ftot,
                                          const int* __restrict__ fslab,
                                          int fb, const uint4* __restrict__ Hs4,
                                          int (*acc)[17], int tid) {
#pragma unroll
    for (int p = 0; p < NREG; p += 2) {
        const int* r0 = fslab + (size_t)(fb * NREG + p) * FCAP2;
        const int* r1 = fslab + (size_t)(fb * NREG + p + 1) * FCAP2;
        gather_pair(r0, ftot[fb * NREG + p], r1, ftot[fb * NREG + p + 1], Hs4, acc, tid);
    }
}

// ---------------- conv1: gather + finalize + fused @W2*dinv -> Hs2 (f16) ----------------
__global__ void __launch_bounds__(BLK, 4)
k_bconv1(const int* __restrict__ ftot, const int* __restrict__ fslab,
         const __half* __restrict__ Hs, const int* __restrict__ deg,
         const float* __restrict__ b0, const float* __restrict__ w2,
         __half* __restrict__ Hs2, int n) {
    __shared__ int acc[SROWS][17];
    __shared__ float w2s[16 * 16];
    __shared__ float b0s[16];
    int tid = threadIdx.x;
    for (int t = tid; t < SROWS * 17; t += BLK) ((int*)acc)[t] = 0;
    w2s[tid] = w2[tid];          // BLK == 256 == 16*16
    if (tid < 16) b0s[tid] = b0[tid];
    __syncthreads();
    int fb = blockIdx.x;
    gather_fb(ftot, fslab, fb, reinterpret_cast<const uint4*>(Hs), acc, tid);
    __syncthreads();
    int nd = (fb >> 3) * CNODES + (fb & 7) * SROWS + tid;
    if (tid < SROWS && nd < n) {
        float dv = rsqrtf((float)deg[nd] + 1.0f);
        const __half* hrow = Hs + (size_t)nd * 16;
        float h1[16];
#pragma unroll
        for (int c = 0; c < 16; ++c) {
            float v = dv * ((float)acc[tid][c] * FXI + __half2float(hrow[c])) + b0s[c];
            h1[c] = v > 0.f ? v : 0.f;
        }
        float o[16];
#pragma unroll
        for (int c2 = 0; c2 < 16; ++c2) {
            float sum = 0.f;
#pragma unroll
            for (int c = 0; c < 16; ++c) sum += h1[c] * w2s[c * 16 + c2];
            o[c2] = sum * dv;
        }
        union { __half2 h[8]; uint4 u[2]; } pk;
#pragma unroll
        for (int k = 0; k < 8; ++k) pk.h[k] = __floats2half2_rn(o[2 * k], o[2 * k + 1]);
        uint4* dp = reinterpret_cast<uint4*>(Hs2 + (size_t)nd * 16);
        dp[0] = pk.u[0];
        dp[1] = pk.u[1];
    }
}

// ---------------- conv2: gather + finalize + fused heads -> out ----------------
__global__ void __launch_bounds__(BLK, 4)
k_bconv2(const int* __restrict__ ftot, const int* __restrict__ fslab,
         const __half* __restrict__ Hs, const int* __restrict__ deg,
         const float* __restrict__ b2,
         const float* __restrict__ w_mem, const float* __restrict__ b_mem,
         const float* __restrict__ w_node, const float* __restrict__ b_node,
         float* __restrict__ out, int n) {
    __shared__ int acc[SROWS][17];
    __shared__ float wms[16], wn0[16], wn1[16], b2s[16];
    int tid = threadIdx.x;
    for (int t = tid; t < SROWS * 17; t += BLK) ((int*)acc)[t] = 0;
    if (tid < 16) {
        wms[tid] = w_mem[tid];
        wn0[tid] = w_node[tid * 2 + 0];
        wn1[tid] = w_node[tid * 2 + 1];
        b2s[tid] = b2[tid];
    }
    __syncthreads();
    int fb = blockIdx.x;
    gather_fb(ftot, fslab, fb, reinterpret_cast<const uint4*>(Hs), acc, tid);
    __syncthreads();
    int nd = (fb >> 3) * CNODES + (fb & 7) * SROWS + tid;
    if (tid < SROWS && nd < n) {
        float dv = rsqrtf((float)deg[nd] + 1.0f);
        const __half* hrow = Hs + (size_t)nd * 16;
        float mph = b_mem[0];
        float n0 = b_node[0];
        float n1 = b_node[1];
#pragma unroll
        for (int c = 0; c < 16; ++c) {
            float v = dv * ((float)acc[tid][c] * FXI + __half2float(hrow[c])) + b2s[c];
            float h = v > 0.f ? v : 0.f;
            mph += h * wms[c];
            n0  += h * wn0[c];
            n1  += h * wn1[c];
        }
        out[nd] = mph;
        out[n + 2 * nd + 0] = n0;
        out[n + 2 * nd + 1] = n1;
    }
}

extern "C" void kernel_launch(void* const* d_in, const int* in_sizes, int n_in,
                              void* d_out, int out_size, void* d_ws, size_t ws_size,
                              hipStream_t stream) {
    const int*   edges     = (const int*)d_in[0];
    const int*   feat      = (const int*)d_in[1];
    const float* emb_user  = (const float*)d_in[2];
    const float* emb_known = (const float*)d_in[3];
    const float* w_user    = (const float*)d_in[4];
    const float* b_user    = (const float*)d_in[5];
    const float* emb_cat   = (const float*)d_in[6];
    const float* w_cat     = (const float*)d_in[7];
    const float* b_cat     = (const float*)d_in[8];
    const float* w0        = (const float*)d_in[9];
    const float* b0        = (const float*)d_in[10];
    const float* w2        = (const float*)d_in[11];
    const float* b2        = (const float*)d_in[12];
    const float* w_node    = (const float*)d_in[13];
    const float* b_node    = (const float*)d_in[14];
    const float* w_mem     = (const float*)d_in[15];
    const float* b_mem     = (const float*)d_in[16];

    const int E = in_sizes[0] / 2;
    const int n = in_sizes[1] / 3;
    const int user_max = in_sizes[2] / 8 - 1;
    const int cat_max  = in_sizes[6] / 4 - 1;
    const int NBC = cdiv(n, CNODES);   // 98 for n=100000
    const int NBF = NBC * 8;           // 784 fine buckets

    const int* src = edges;
    const int* dst = edges + E;

    // workspace layout
    int* cslab   = (int*)d_ws;                                  // NBC*NREG*CAPR (~16.9 MB)
    int* fslab   = cslab + (size_t)NBC * NREG * CAPR;           // NBF*NREG*FCAP2 (~19.3 MB)
    __half* hsA  = (__half*)(fslab + (size_t)NBF * NREG * FCAP2);
    __half* hsB  = hsA + (size_t)n * 16;
    int* gcur    = (int*)(hsB + (size_t)n * 16);                // NBC*NREG
    int* ovf_cnt = gcur + (size_t)NBC * NREG;                   // 1
    int* deg     = ovf_cnt + 1;                                 // n   (zeroed with gcur/ovf_cnt)
    int* ovf_b   = deg + n;                                     // OVFCAP
    int* ovf_e   = ovf_b + OVFCAP;                              // OVFCAP
    int* ftot    = ovf_e + OVFCAP;                              // NBF*NREG

    float* outp = (float*)d_out;

    hipMemsetAsync(gcur, 0, (size_t)(NBC * NREG + 1 + n) * sizeof(int), stream);
    k_bucket<<<NPB, PBLK, 0, stream>>>(src, dst, gcur, cslab,
                                       ovf_cnt, ovf_b, ovf_e, E, NBC);
    k_refine<<<NBC * NREG, PBLK, 0, stream>>>(gcur, cslab, fslab, ftot, deg,
                                              ovf_cnt, ovf_b, ovf_e, n);
    k_featmm<<<cdiv(n, BLK), BLK, 0, stream>>>(feat, emb_user, emb_known, w_user, b_user,
                                               emb_cat, w_cat, b_cat, w0, deg, hsA,
                                               n, user_max, cat_max);
    k_bconv1<<<NBF, BLK, 0, stream>>>(ftot, fslab, hsA, deg, b0, w2, hsB, n);
    k_bconv2<<<NBF, BLK, 0, stream>>>(ftot, fslab, hsB, deg, b2,
                                      w_mem, b_mem, w_node, b_node, outp, n);
}

// Round 16
// 109.194 us; speedup vs baseline: 1.0842x; 1.0842x over previous
//
#include <hip/hip_runtime.h>
#include <hip/hip_fp16.h>

#define BLK 256
#define PBLK 1024             // threads per partition block
#define NPB 256               // partition blocks == chunks
#define CSHIFT 10             // 1024 dst nodes per coarse bucket
#define CNODES 1024
#define CMASK 1023
#define NBCMAX 128            // max coarse buckets (n <= 131072)
#define CAP 40960             // coarse slab slots per bucket (multiple of 16)
#define SSHIFT 6              // slice bits 6..9 -> 16 slices of 64 nodes
#define NSL 16
#define SROWS 64
#define SRMASK 63
#define NCHK 8                // positional chunks per bucket for refine
#define FCAP2 384             // slots per (bucket,slice,chunk); mean ~255, +8 sigma
#define FXS 1048576.0f        // 2^20 fixed-point scale for LDS int accumulation
#define FXI (1.0f / 1048576.0f)

typedef int v4i __attribute__((ext_vector_type(4)));

static inline int cdiv(int a, int b) { return (a + b - 1) / b; }

// ---------------- pass A: per-chunk coarse-bucket histogram ----------------
__global__ void __launch_bounds__(PBLK)
k_hist(const int* __restrict__ dst, int* __restrict__ histG, int e, int nb) {
    __shared__ int h[NBCMAX];
    int tid = threadIdx.x;
    for (int t = tid; t < nb; t += PBLK) h[t] = 0;
    __syncthreads();
    int per = ((e + (int)gridDim.x - 1) / (int)gridDim.x + 3) & ~3;
    int beg = blockIdx.x * per;
    int end = min(e, beg + per);
    if (beg < end) {
        int m4 = beg + ((end - beg) & ~3);
        for (int i = beg + tid * 4; i < m4; i += PBLK * 4) {
            v4i d4 = __builtin_nontemporal_load((const v4i*)(dst + i));
            atomicAdd(&h[d4[0] >> CSHIFT], 1);
            atomicAdd(&h[d4[1] >> CSHIFT], 1);
            atomicAdd(&h[d4[2] >> CSHIFT], 1);
            atomicAdd(&h[d4[3] >> CSHIFT], 1);
        }
        int it = m4 + tid;
        if (it < end) atomicAdd(&h[dst[it] >> CSHIFT], 1);
    }
    __syncthreads();
    for (int t = tid; t < nb; t += PBLK) histG[(size_t)blockIdx.x * nb + t] = h[t];
}

// ---------------- pass B: per-bucket scan of chunk counts (runs padded to 16) ----------------
__global__ void __launch_bounds__(NPB)
k_base(const int* __restrict__ histG, int* __restrict__ baseG, int* __restrict__ tot, int nb) {
    __shared__ int s[NPB];
    int b = blockIdx.x;
    int t = threadIdx.x;
    int hc = histG[(size_t)t * nb + b];
    int r = (hc + 15) & ~15;
    s[t] = r;
    __syncthreads();
    for (int off = 1; off < NPB; off <<= 1) {
        int v = (t >= off) ? s[t - off] : 0;
        __syncthreads();
        s[t] += v;
        __syncthreads();
    }
    int excl = s[t] - r;
    baseG[(size_t)t * nb + b] = b * CAP + excl;
    if (t == NPB - 1) tot[b] = min(s[t], CAP);
}

// ---------------- pass C: coarse scatter, block-private LDS cursors ----------------
__global__ void __launch_bounds__(PBLK)
k_scatter(const int* __restrict__ src, const int* __restrict__ dst,
          const int* __restrict__ baseG, int* __restrict__ slab, int e, int nb) {
    __shared__ int cur[NBCMAX];
    int tid = threadIdx.x;
    int blk = blockIdx.x;
    for (int t = tid; t < nb; t += PBLK) cur[t] = baseG[(size_t)blk * nb + t];
    __syncthreads();
    int per = ((e + (int)gridDim.x - 1) / (int)gridDim.x + 3) & ~3;   // must match k_hist
    int beg = blk * per;
    int end = min(e, beg + per);
    if (beg < end) {
        int m4 = beg + ((end - beg) & ~3);
        for (int i = beg + tid * 4; i < m4; i += PBLK * 4) {
            v4i s4 = __builtin_nontemporal_load((const v4i*)(src + i));
            v4i d4 = __builtin_nontemporal_load((const v4i*)(dst + i));
#pragma unroll
            for (int k = 0; k < 4; ++k) {
                int d = d4[k];
                int b = d >> CSHIFT;
                int pos = atomicAdd(&cur[b], 1);
                if (pos < (b + 1) * CAP) slab[pos] = (s4[k] << CSHIFT) | (d & CMASK);
            }
        }
        int it = m4 + tid;
        if (it < end) {
            int d = dst[it];
            int b = d >> CSHIFT;
            int pos = atomicAdd(&cur[b], 1);
            if (pos < (b + 1) * CAP) slab[pos] = (src[it] << CSHIFT) | (d & CMASK);
        }
    }
    __syncthreads();
    for (int bb = tid; bb < nb; bb += PBLK) {
        int c = cur[bb];
        int lim = (bb + 1) * CAP;
        while ((c & 15) && c < lim) slab[c++] = -1;
    }
}

// ---------------- pass D: chunked refine -> 16 fine segments per (bucket,chunk) + degree ----------------
__global__ void __launch_bounds__(PBLK)
k_refine(const int* __restrict__ tot, const int* __restrict__ cslab,
         int* __restrict__ fslab, int* __restrict__ ftot,
         int* __restrict__ deg, int n) {
    __shared__ int cur[NSL];
    __shared__ int cnt[CNODES];
    int tid = threadIdx.x;
    int b = blockIdx.x >> 3;
    int p = blockIdx.x & 7;
    if (tid < NSL) cur[tid] = 0;
    for (int t = tid; t < CNODES; t += PBLK) cnt[t] = 0;
    __syncthreads();
    int nlines = tot[b] >> 4;                 // tot is a multiple of 16
    int q0 = ((p * nlines) >> 3) << 2;        // chunk start, int4 units (16-aligned slots)
    int q1 = (((p + 1) * nlines) >> 3) << 2;  // chunk end
    const v4i* sl4 = reinterpret_cast<const v4i*>(cslab + (size_t)b * CAP);
    for (int i = q0 + tid; i < q1; i += PBLK) {
        v4i e4 = sl4[i];
#pragma unroll
        for (int k = 0; k < 4; ++k) {
            int e = e4[k];
            if (e >= 0) {
                int s = (e >> SSHIFT) & (NSL - 1);
                int fe = ((e >> CSHIFT) << SSHIFT) | (e & SRMASK);
                atomicAdd(&cnt[e & CMASK], 1);
                int pos = atomicAdd(&cur[s], 1);
                if (pos < FCAP2) fslab[(size_t)((b * NSL + s) * NCHK + p) * FCAP2 + pos] = fe;
            }
        }
    }
    __syncthreads();
    if (tid < NSL) {
        int cc = min(cur[tid], FCAP2);
        int r = min((cc + 15) & ~15, FCAP2);
        int* seg = fslab + (size_t)((b * NSL + tid) * NCHK + p) * FCAP2;
        for (int x = cc; x < r; ++x) seg[x] = -1;
        ftot[(b * NSL + tid) * NCHK + p] = r;
    }
    for (int t = tid; t < CNODES; t += PBLK) {
        int v = cnt[t];
        int nd = b * CNODES + t;
        if (v && nd < n) atomicAdd(&deg[nd], v);
    }
}

// ---------------- fused: feature encode -> @W0 -> *dinv -> Hs[n,16] (f16) ----------------
__global__ void k_featmm(const int* __restrict__ feat,
                         const float* __restrict__ emb_user,
                         const float* __restrict__ emb_known,
                         const float* __restrict__ w_user,
                         const float* __restrict__ b_user,
                         const float* __restrict__ emb_cat,
                         const float* __restrict__ w_cat,
                         const float* __restrict__ b_cat,
                         const float* __restrict__ w0,
                         const int* __restrict__ deg,
                         __half* __restrict__ Hs,
                         int n, int user_max, int cat_max) {
    __shared__ float w0s[8 * 16];
    for (int t = threadIdx.x; t < 8 * 16; t += blockDim.x) w0s[t] = w0[t];
    __syncthreads();
    int i = blockIdx.x * blockDim.x + threadIdx.x;
    if (i >= n) return;
    int col0 = feat[i * 3 + 0];
    int col1 = feat[i * 3 + 1];
    int typ  = feat[i * 3 + 2];
    float x[8];
    if (typ == 0) {
        int u = min(max(col0, 0), user_max);
        int k = min(max(col1, 0), 1);
        const float4* eu = reinterpret_cast<const float4*>(emb_user + (size_t)u * 8);
        const float4* ek = reinterpret_cast<const float4*>(emb_known + (size_t)k * 8);
        float4 a0 = eu[0], a1 = eu[1], k0 = ek[0], k1 = ek[1];
        float in[8];
        in[0] = fmaxf(a0.x + k0.x, 0.f); in[1] = fmaxf(a0.y + k0.y, 0.f);
        in[2] = fmaxf(a0.z + k0.z, 0.f); in[3] = fmaxf(a0.w + k0.w, 0.f);
        in[4] = fmaxf(a1.x + k1.x, 0.f); in[5] = fmaxf(a1.y + k1.y, 0.f);
        in[6] = fmaxf(a1.z + k1.z, 0.f); in[7] = fmaxf(a1.w + k1.w, 0.f);
#pragma unroll
        for (int c = 0; c < 8; ++c) {
            float s = b_user[c];
#pragma unroll
            for (int d = 0; d < 8; ++d) s += in[d] * w_user[d * 8 + c];
            x[c] = s;
        }
    } else {
        int ci = min(max(col0, 0), cat_max);
        float4 c0 = reinterpret_cast<const float4*>(emb_cat + (size_t)ci * 4)[0];
        float in[4];
        in[0] = fmaxf(c0.x, 0.f); in[1] = fmaxf(c0.y, 0.f);
        in[2] = fmaxf(c0.z, 0.f); in[3] = fmaxf(c0.w, 0.f);
#pragma unroll
        for (int c = 0; c < 8; ++c) {
            float s = b_cat[c];
#pragma unroll
            for (int d = 0; d < 4; ++d) s += in[d] * w_cat[d * 8 + c];
            x[c] = s;
        }
    }
    float dv = rsqrtf((float)deg[i] + 1.0f);
    float o[16];
#pragma unroll
    for (int c = 0; c < 16; ++c) {
        float s = 0.f;
#pragma unroll
        for (int d = 0; d < 8; ++d) s += x[d] * w0s[d * 16 + c];
        o[c] = s * dv;
    }
    union { __half2 h[8]; uint4 u[2]; } pk;
#pragma unroll
    for (int k = 0; k < 8; ++k) pk.h[k] = __floats2half2_rn(o[2 * k], o[2 * k + 1]);
    uint4* dp = reinterpret_cast<uint4*>(Hs + (size_t)i * 16);
    dp[0] = pk.u[0];
    dp[1] = pk.u[1];
}

// ---------------- paired-segment 8-deep gather ----------------
__device__ __forceinline__ void gather_pair(const int* __restrict__ run0, int n0,
                                            const int* __restrict__ run1, int n1,
                                            const uint4* __restrict__ Hs4,
                                            int (*acc)[17], int tid) {
    const v4i* sl0 = reinterpret_cast<const v4i*>(run0);
    const v4i* sl1 = reinterpret_cast<const v4i*>(run1);
    int ns0 = n0 >> 2, ns1 = n1 >> 2;
    int maxs = max(ns0, ns1);
    int g = tid >> 1, q = tid & 1;    // 128 lane-pairs; q owns 8 of 16 channels
    for (int base = 0; base < maxs; base += 128) {
        int i = base + g;
        v4i e0 = sl0[min(i, (FCAP2 >> 2) - 1)];
        v4i e1 = sl1[min(i, (FCAP2 >> 2) - 1)];
        bool b0 = i < ns0, b1 = i < ns1;
        int us[8];
        us[0] = b0 ? e0[0] : -1; us[1] = b0 ? e0[1] : -1;
        us[2] = b0 ? e0[2] : -1; us[3] = b0 ? e0[3] : -1;
        us[4] = b1 ? e1[0] : -1; us[5] = b1 ? e1[1] : -1;
        us[6] = b1 ? e1[2] : -1; us[7] = b1 ? e1[3] : -1;
        uint4 v[8];
#pragma unroll
        for (int k = 0; k < 8; ++k)
            if (us[k] >= 0) v[k] = Hs4[(size_t)(us[k] >> SSHIFT) * 2 + q];
#pragma unroll
        for (int k = 0; k < 8; ++k) {
            if (us[k] >= 0) {
                int dl = us[k] & SRMASK;
                union { uint4 u4; __half2 h[4]; } c;
                c.u4 = v[k];
#pragma unroll
                for (int j = 0; j < 4; ++j) {
                    float2 f = __half22float2(c.h[j]);
                    atomicAdd(&acc[dl][8 * q + 2 * j + 0], __float2int_rn(f.x * FXS));
                    atomicAdd(&acc[dl][8 * q + 2 * j + 1], __float2int_rn(f.y * FXS));
                }
            }
        }
    }
}

__device__ __forceinline__ void gather_fb(const int* __restrict__ ftot,
                                          const int* __restrict__ fslab,
                                          int fb, const uint4* __restrict__ Hs4,
                                          int (*acc)[17], int tid) {
#pragma unroll
    for (int p = 0; p < NCHK; p += 2) {
        const int* r0 = fslab + (size_t)(fb * NCHK + p) * FCAP2;
        const int* r1 = fslab + (size_t)(fb * NCHK + p + 1) * FCAP2;
        gather_pair(r0, ftot[fb * NCHK + p], r1, ftot[fb * NCHK + p + 1], Hs4, acc, tid);
    }
}

// ---------------- conv1: gather + finalize + fused @W2*dinv -> Hs2 (f16) ----------------
__global__ void __launch_bounds__(BLK, 8)
k_bconv1(const int* __restrict__ ftot, const int* __restrict__ fslab,
         const __half* __restrict__ Hs, const int* __restrict__ deg,
         const float* __restrict__ b0, const float* __restrict__ w2,
         __half* __restrict__ Hs2, int n) {
    __shared__ int acc[SROWS][17];
    __shared__ float w2s[16 * 16];
    __shared__ float b0s[16];
    int tid = threadIdx.x;
    for (int t = tid; t < SROWS * 17; t += BLK) ((int*)acc)[t] = 0;
    w2s[tid] = w2[tid];          // BLK == 256 == 16*16
    if (tid < 16) b0s[tid] = b0[tid];
    __syncthreads();
    int fb = blockIdx.x;
    gather_fb(ftot, fslab, fb, reinterpret_cast<const uint4*>(Hs), acc, tid);
    __syncthreads();
    int nd = (fb >> 4) * CNODES + (fb & (NSL - 1)) * SROWS + tid;
    if (tid < SROWS && nd < n) {
        float dv = rsqrtf((float)deg[nd] + 1.0f);
        const __half* hrow = Hs + (size_t)nd * 16;
        float h1[16];
#pragma unroll
        for (int c = 0; c < 16; ++c) {
            float v = dv * ((float)acc[tid][c] * FXI + __half2float(hrow[c])) + b0s[c];
            h1[c] = v > 0.f ? v : 0.f;
        }
        float o[16];
#pragma unroll
        for (int c2 = 0; c2 < 16; ++c2) {
            float sum = 0.f;
#pragma unroll
            for (int c = 0; c < 16; ++c) sum += h1[c] * w2s[c * 16 + c2];
            o[c2] = sum * dv;
        }
        union { __half2 h[8]; uint4 u[2]; } pk;
#pragma unroll
        for (int k = 0; k < 8; ++k) pk.h[k] = __floats2half2_rn(o[2 * k], o[2 * k + 1]);
        uint4* dp = reinterpret_cast<uint4*>(Hs2 + (size_t)nd * 16);
        dp[0] = pk.u[0];
        dp[1] = pk.u[1];
    }
}

// ---------------- conv2: gather + finalize + fused heads -> out ----------------
__global__ void __launch_bounds__(BLK, 8)
k_bconv2(const int* __restrict__ ftot, const int* __restrict__ fslab,
         const __half* __restrict__ Hs, const int* __restrict__ deg,
         const float* __restrict__ b2,
         const float* __restrict__ w_mem, const float* __restrict__ b_mem,
         const float* __restrict__ w_node, const float* __restrict__ b_node,
         float* __restrict__ out, int n) {
    __shared__ int acc[SROWS][17];
    __shared__ float wms[16], wn0[16], wn1[16], b2s[16];
    int tid = threadIdx.x;
    for (int t = tid; t < SROWS * 17; t += BLK) ((int*)acc)[t] = 0;
    if (tid < 16) {
        wms[tid] = w_mem[tid];
        wn0[tid] = w_node[tid * 2 + 0];
        wn1[tid] = w_node[tid * 2 + 1];
        b2s[tid] = b2[tid];
    }
    __syncthreads();
    int fb = blockIdx.x;
    gather_fb(ftot, fslab, fb, reinterpret_cast<const uint4*>(Hs), acc, tid);
    __syncthreads();
    int nd = (fb >> 4) * CNODES + (fb & (NSL - 1)) * SROWS + tid;
    if (tid < SROWS && nd < n) {
        float dv = rsqrtf((float)deg[nd] + 1.0f);
        const __half* hrow = Hs + (size_t)nd * 16;
        float mph = b_mem[0];
        float n0 = b_node[0];
        float n1 = b_node[1];
#pragma unroll
        for (int c = 0; c < 16; ++c) {
            float v = dv * ((float)acc[tid][c] * FXI + __half2float(hrow[c])) + b2s[c];
            float h = v > 0.f ? v : 0.f;
            mph += h * wms[c];
            n0  += h * wn0[c];
            n1  += h * wn1[c];
        }
        out[nd] = mph;
        out[n + 2 * nd + 0] = n0;
        out[n + 2 * nd + 1] = n1;
    }
}

extern "C" void kernel_launch(void* const* d_in, const int* in_sizes, int n_in,
                              void* d_out, int out_size, void* d_ws, size_t ws_size,
                              hipStream_t stream) {
    const int*   edges     = (const int*)d_in[0];
    const int*   feat      = (const int*)d_in[1];
    const float* emb_user  = (const float*)d_in[2];
    const float* emb_known = (const float*)d_in[3];
    const float* w_user    = (const float*)d_in[4];
    const float* b_user    = (const float*)d_in[5];
    const float* emb_cat   = (const float*)d_in[6];
    const float* w_cat     = (const float*)d_in[7];
    const float* b_cat     = (const float*)d_in[8];
    const float* w0        = (const float*)d_in[9];
    const float* b0        = (const float*)d_in[10];
    const float* w2        = (const float*)d_in[11];
    const float* b2        = (const float*)d_in[12];
    const float* w_node    = (const float*)d_in[13];
    const float* b_node    = (const float*)d_in[14];
    const float* w_mem     = (const float*)d_in[15];
    const float* b_mem     = (const float*)d_in[16];

    const int E = in_sizes[0] / 2;
    const int n = in_sizes[1] / 3;
    const int user_max = in_sizes[2] / 8 - 1;
    const int cat_max  = in_sizes[6] / 4 - 1;
    const int NBC = cdiv(n, CNODES);   // 98 for n=100000
    const int NBF = NBC * NSL;         // 1568 fine buckets

    const int* src = edges;
    const int* dst = edges + E;

    // workspace layout
    int* cslab   = (int*)d_ws;                                 // NBC*CAP (~16 MB)
    int* fslab   = cslab + (size_t)NBC * CAP;                  // NBF*NCHK*FCAP2 (~19.3 MB)
    __half* hsA  = (__half*)(fslab + (size_t)NBF * NCHK * FCAP2); // 16n halfs
    __half* hsB  = hsA + (size_t)n * 16;                       // 16n halfs
    int* histG   = (int*)(hsB + (size_t)n * 16);               // NPB*NBC
    int* baseG   = histG + (size_t)NPB * NBC;                  // NPB*NBC
    int* tot     = baseG + (size_t)NPB * NBC;                  // NBC
    int* deg     = tot + NBC;                                  // n
    int* ftot    = deg + n;                                    // NBF*NCHK

    float* outp = (float*)d_out;

    hipMemsetAsync(deg, 0, (size_t)n * sizeof(int), stream);
    k_hist<<<NPB, PBLK, 0, stream>>>(dst, histG, E, NBC);
    k_base<<<NBC, NPB, 0, stream>>>(histG, baseG, tot, NBC);
    k_scatter<<<NPB, PBLK, 0, stream>>>(src, dst, baseG, cslab, E, NBC);
    k_refine<<<NBC * NCHK, PBLK, 0, stream>>>(tot, cslab, fslab, ftot, deg, n);
    k_featmm<<<cdiv(n, BLK), BLK, 0, stream>>>(feat, emb_user, emb_known, w_user, b_user,
                                               emb_cat, w_cat, b_cat, w0, deg, hsA,
                                               n, user_max, cat_max);
    k_bconv1<<<NBF, BLK, 0, stream>>>(ftot, fslab, hsA, deg, b0, w2, hsB, n);
    k_bconv2<<<NBF, BLK, 0, stream>>>(ftot, fslab, hsB, deg, b2,
                                      w_mem, b_mem, w_node, b_node, outp, n);
}